// Round 11
// baseline (720.799 us; speedup 1.0000x reference)
//
#include <hip/hip_runtime.h>

// EGNN layer (CamadaEquivariante), round 11:
//  - scatter writes 32B slot record [r,c,-,-,ea01,ea23,ea45,ea67(bf16)];
//    edge reads rec sequentially -> eattr random gather + perm eliminated.
//  - wprep+hist merged; single-block chunked scan (r7-proven) -> 7 launches.
//  - edge_mfma: in-place LDS tile, 2 barriers, ea-frag via v_perm/v_alignbit.
//  - pre_mfma / aggnode unchanged (known-good).
// ws ~= 90 MB. Fallback to atomic path if ws too small.

typedef unsigned int uint;
typedef unsigned short u16;
typedef __attribute__((ext_vector_type(8))) short short8;
typedef __attribute__((ext_vector_type(4))) float f32x4;

#define UB_LO(u) __uint_as_float((u) << 16)
#define UB_HI(u) __uint_as_float((u) & 0xffff0000u)

__device__ __forceinline__ float fast_tanh(float x) {
    float e = __expf(2.0f * x);
    return 1.0f - 2.0f * __builtin_amdgcn_rcpf(e + 1.0f);
}
__device__ __forceinline__ u16 bf16rne(float f) {
    uint u = __float_as_uint(f);
    return (u16)((u + 0x7fffu + ((u >> 16) & 1u)) >> 16);
}
__device__ __forceinline__ uint packbf(float a, float b) {
    return (uint)bf16rne(a) | ((uint)bf16rne(b) << 16);
}
// 1-inst truncating bf16x2 pack: lo16 = hi16(a), hi16 = hi16(b)
__device__ __forceinline__ uint packbf_fast(float a, float b) {
    return __builtin_amdgcn_perm(__float_as_uint(b), __float_as_uint(a), 0x07060302u);
}
__device__ __forceinline__ u16 trunc16(float f) {
    return (u16)(__float_as_uint(f) >> 16);
}
// XOR-swizzle within a [64][64]-bf16 (128B-row) LDS tile: byte ^= ((row&7)<<4)
__device__ __forceinline__ int swzb(int b) { return b ^ ((b >> 3) & 0x70); }

// ---------------------------------------- weight transpose + edge histogram ---
__global__ void wprep_hist_kernel(const float* __restrict__ we_w1, const float* __restrict__ we_w2,
                                  const float* __restrict__ wx_w1, const float* __restrict__ wv_w1,
                                  const float* __restrict__ wh_w1, const float* __restrict__ wh_w2,
                                  u16* __restrict__ we1t, u16* __restrict__ we2t,
                                  u16* __restrict__ wx1t, u16* __restrict__ wv1t,
                                  u16* __restrict__ wh1t, u16* __restrict__ wh2t,
                                  u16* __restrict__ wert,
                                  const int* __restrict__ rows, int* __restrict__ hist, int E) {
    const int b = blockIdx.x;
    if (b < 32) {
        int t = b * 256 + threadIdx.x;
        if (t < 8192) {
            int j = t >> 7, k = t & 127;
            we1t[t] = bf16rne(we_w1[k * 64 + j]);
            wh1t[t] = bf16rne(wh_w1[k * 64 + j]);
        }
        if (t < 4096) {
            int n = t >> 6, k = t & 63;
            we2t[t] = bf16rne(we_w2[k * 64 + n]);
            wx1t[t] = bf16rne(wx_w1[k * 64 + n]);
            wv1t[t] = bf16rne(wv_w1[k * 64 + n]);
            wh2t[t] = bf16rne(wh_w2[k * 64 + n]);
        }
        if (t < 2048) {      // wert[n][k], k=0 -> rad row (128), k=1..8 -> rows 129..136
            int n = t >> 5, k = t & 31;
            float v = 0.0f;
            if (k == 0) v = we_w1[128 * 64 + n];
            else if (k <= 8) v = we_w1[(128 + k) * 64 + n];
            wert[t] = bf16rne(v);
        }
    } else {
        int e = (b - 32) * 256 + threadIdx.x;
        if (e < E) atomicAdd(&hist[rows[e]], 1);
    }
}

// --------------------------------------------------------- pre MFMA kernel ---
__global__ __launch_bounds__(256, 2)
void pre_mfma_kernel(const float* __restrict__ h, const float* __restrict__ we_b1,
                     const u16* __restrict__ we1t,
                     u16* __restrict__ HrB, u16* __restrict__ HcB, int N)
{
    __shared__ u16 X1[4096];
    __shared__ u16 X2[4096];
    const int tid = threadIdx.x, lane = tid & 63, wv = tid >> 6;
    const int nb = blockIdx.x * 64;
    const int el = tid >> 2, jg = tid & 3;
    const int fn = lane & 15, fk8 = (lane >> 4) * 8;

    {
        uint pk[8];
        if (nb + el < N) {
            const float4* h4 = (const float4*)(h + (size_t)(nb + el) * 64 + jg * 16);
            #pragma unroll
            for (int q = 0; q < 4; q++) {
                float4 v = h4[q];
                pk[2*q]   = packbf_fast(v.x, v.y);
                pk[2*q+1] = packbf_fast(v.z, v.w);
            }
        } else {
            #pragma unroll
            for (int q = 0; q < 8; q++) pk[q] = 0;
        }
        const int b0 = swzb(el * 128 + jg * 32), b1 = swzb(el * 128 + jg * 32 + 16);
        *(uint4*)(&X1[b0 >> 1]) = make_uint4(pk[0], pk[1], pk[2], pk[3]);
        *(uint4*)(&X1[b1 >> 1]) = make_uint4(pk[4], pk[5], pk[6], pk[7]);
    }
    __syncthreads();

    const int mb = wv * 16;
    short8 a0, a1;
    {
        const int ba = swzb((mb + fn) * 128 + fk8 * 2);
        const int bb = swzb((mb + fn) * 128 + 64 + fk8 * 2);
        a0 = *(const short8*)(&X1[ba >> 1]);
        a1 = *(const short8*)(&X1[bb >> 1]);
    }
    // Hr = h @ We1[0:64] + b1
    #pragma unroll
    for (int n0 = 0; n0 < 4; n0++) {
        uint4 bw0 = *(const uint4*)(we1t + (n0*16 + fn) * 128 + fk8);
        uint4 bw1 = *(const uint4*)(we1t + (n0*16 + fn) * 128 + 32 + fk8);
        const float bias = we_b1[n0 * 16 + fn];
        f32x4 q = {bias, bias, bias, bias};
        q = __builtin_amdgcn_mfma_f32_16x16x32_bf16(a0, __builtin_bit_cast(short8, bw0), q, 0, 0, 0);
        q = __builtin_amdgcn_mfma_f32_16x16x32_bf16(a1, __builtin_bit_cast(short8, bw1), q, 0, 0, 0);
        #pragma unroll
        for (int r2 = 0; r2 < 4; r2++) {
            const int m = mb + (lane >> 4) * 4 + r2;
            X2[swzb(m * 128 + (n0*16 + fn) * 2) >> 1] = bf16rne(q[r2]);
        }
    }
    __syncthreads();
    if (nb + el < N) {
        const int b0 = swzb(el * 128 + jg * 32), b1 = swzb(el * 128 + jg * 32 + 16);
        uint4 v0 = *(const uint4*)(&X2[b0 >> 1]);
        uint4 v1 = *(const uint4*)(&X2[b1 >> 1]);
        u16* o = HrB + (size_t)(nb + el) * 64 + jg * 16;
        *(uint4*)o = v0; *(uint4*)(o + 8) = v1;
    }
    __syncthreads();
    // Hc = h @ We1[64:128]
    #pragma unroll
    for (int n0 = 0; n0 < 4; n0++) {
        uint4 bw0 = *(const uint4*)(we1t + (n0*16 + fn) * 128 + 64 + fk8);
        uint4 bw1 = *(const uint4*)(we1t + (n0*16 + fn) * 128 + 96 + fk8);
        f32x4 q = {0.f, 0.f, 0.f, 0.f};
        q = __builtin_amdgcn_mfma_f32_16x16x32_bf16(a0, __builtin_bit_cast(short8, bw0), q, 0, 0, 0);
        q = __builtin_amdgcn_mfma_f32_16x16x32_bf16(a1, __builtin_bit_cast(short8, bw1), q, 0, 0, 0);
        #pragma unroll
        for (int r2 = 0; r2 < 4; r2++) {
            const int m = mb + (lane >> 4) * 4 + r2;
            X2[swzb(m * 128 + (n0*16 + fn) * 2) >> 1] = bf16rne(q[r2]);
        }
    }
    __syncthreads();
    if (nb + el < N) {
        const int b0 = swzb(el * 128 + jg * 32), b1 = swzb(el * 128 + jg * 32 + 16);
        uint4 v0 = *(const uint4*)(&X2[b0 >> 1]);
        uint4 v1 = *(const uint4*)(&X2[b1 >> 1]);
        u16* o = HcB + (size_t)(nb + el) * 64 + jg * 16;
        *(uint4*)o = v0; *(uint4*)(o + 8) = v1;
    }
}

// --------------------------------------------------------- edge MFMA kernel ---
// Slot order + XCD-chunked swizzle. Single in-place tile T: Xp -> X1 -> X2.
// rec[slot]: [r, c, -, -, ea01, ea23, ea45, ea67] (32B, bf16-packed ea).
__global__ __launch_bounds__(256, 8)
void edge_mfma_kernel(const float* __restrict__ x,
                      const uint* __restrict__ rec,
                      const u16* __restrict__ HrB, const u16* __restrict__ HcB,
                      const u16* __restrict__ wert,
                      const u16* __restrict__ we2t, const float* __restrict__ we_b2,
                      const u16* __restrict__ wx1t, const float* __restrict__ wx_b1,
                      const float* __restrict__ wx_w2, const float* __restrict__ wx_b2,
                      float* __restrict__ miF, float* __restrict__ aggF,
                      float* __restrict__ cntF, int E)
{
    __shared__ u16 T[4096];        // Xp -> X1 -> X2 (in place)
    __shared__ float dS[64][3];
    __shared__ float pxS[64];
    __shared__ float radS[64];
    __shared__ int rS[64];

    const int tid = threadIdx.x, lane = tid & 63, wv = tid >> 6;
    int bid = blockIdx.x;
    const int nwg = gridDim.x;
    if ((nwg & 7) == 0) bid = (bid & 7) * (nwg >> 3) + (bid >> 3);  // XCD-chunked
    const int sb = bid * 64;
    const int fn = lane & 15, fk8 = (lane >> 4) * 8;
    const int el = tid >> 2, jg = tid & 3;
    const int s = sb + el;
    const int mb = wv * 16;

    // ---- phase A: T = Hr[r] + Hc[c] (bf16); dS/radS/rS ----
    {
        int r = -1, c = 0;
        if (s < E) { int2 p2 = *(const int2*)(rec + (size_t)s * 8); r = p2.x; c = p2.y; }
        if (jg == 0) rS[el] = r;
        uint pk[8];
        if (s < E) {
            if (jg == 0) {
                const float d0 = x[(size_t)r*3+0] - x[(size_t)c*3+0];
                const float d1 = x[(size_t)r*3+1] - x[(size_t)c*3+1];
                const float d2 = x[(size_t)r*3+2] - x[(size_t)c*3+2];
                dS[el][0] = d0; dS[el][1] = d1; dS[el][2] = d2;
                radS[el] = d0*d0 + d1*d1 + d2*d2;
            }
            uint4 ra = *(const uint4*)(HrB + (size_t)r * 64 + jg * 16);
            uint4 rb = *(const uint4*)(HrB + (size_t)r * 64 + jg * 16 + 8);
            uint4 ca = *(const uint4*)(HcB + (size_t)c * 64 + jg * 16);
            uint4 cb = *(const uint4*)(HcB + (size_t)c * 64 + jg * 16 + 8);
            uint rw[8] = {ra.x, ra.y, ra.z, ra.w, rb.x, rb.y, rb.z, rb.w};
            uint cw[8] = {ca.x, ca.y, ca.z, ca.w, cb.x, cb.y, cb.z, cb.w};
            #pragma unroll
            for (int q = 0; q < 8; q++) {
                const float lo = UB_LO(rw[q]) + UB_LO(cw[q]);
                const float hi = UB_HI(rw[q]) + UB_HI(cw[q]);
                pk[q] = packbf_fast(lo, hi);
            }
        } else {
            #pragma unroll
            for (int q = 0; q < 8; q++) pk[q] = 0;
        }
        const int b0 = swzb(el * 128 + jg * 32), b1 = swzb(el * 128 + jg * 32 + 16);
        *(uint4*)(&T[b0 >> 1]) = make_uint4(pk[0], pk[1], pk[2], pk[3]);
        *(uint4*)(&T[b1 >> 1]) = make_uint4(pk[4], pk[5], pk[6], pk[7]);
    }
    __syncthreads();   // barrier 1: T(Xp)/dS/radS/rS visible

    // ---- ea/rad A-frag: lane fn = edge (mb+fn), k-chunk = lane>>4 ----
    uint ae[4] = {0, 0, 0, 0};
    {
        const int kc = lane >> 4;
        const int s2 = sb + mb + fn;
        if (kc < 2 && s2 < E) {
            const uint4 ue = *(const uint4*)(rec + (size_t)s2 * 8 + 4);
            if (kc == 0) {
                const float rad = radS[mb + fn];
                // ae[0]: lo=bf16(rad), hi=ea0(=lo16(ue.x))
                ae[0] = __builtin_amdgcn_perm(ue.x, __float_as_uint(rad), 0x05040302u);
                ae[1] = __builtin_amdgcn_alignbit(ue.y, ue.x, 16);  // (ea1, ea2)
                ae[2] = __builtin_amdgcn_alignbit(ue.z, ue.y, 16);  // (ea3, ea4)
                ae[3] = __builtin_amdgcn_alignbit(ue.w, ue.z, 16);  // (ea5, ea6)
            } else {
                ae[0] = ue.w >> 16;                                 // (ea7, 0)
            }
        }
    }
    const short8 a_e = __builtin_bit_cast(short8, *(uint4*)ae);

    // ---- layer 1 (in place): q = MFMA(ea, wert); T = tanh(q + T) ----
    #pragma unroll
    for (int n0 = 0; n0 < 4; n0++) {
        uint4 bw = *(const uint4*)(wert + (n0*16 + fn) * 32 + fk8);
        f32x4 q = {0.f, 0.f, 0.f, 0.f};
        q = __builtin_amdgcn_mfma_f32_16x16x32_bf16(a_e, __builtin_bit_cast(short8, bw), q, 0, 0, 0);
        #pragma unroll
        for (int r2 = 0; r2 < 4; r2++) {
            const int idx = swzb((mb + (lane >> 4) * 4 + r2) * 128 + (n0*16 + fn) * 2) >> 1;
            const float pre = q[r2] + UB_LO((uint)T[idx]);
            T[idx] = trunc16(fast_tanh(pre));
        }
    }

    // ---- layer 2 (in place): read own-band frags, write X2 over X1 ----
    short8 a0, a1;
    {
        const int ba = swzb((mb + fn) * 128 + fk8 * 2);
        const int bb = swzb((mb + fn) * 128 + 64 + fk8 * 2);
        a0 = *(const short8*)(&T[ba >> 1]);
        a1 = *(const short8*)(&T[bb >> 1]);
    }
    #pragma unroll
    for (int n0 = 0; n0 < 4; n0++) {
        uint4 bw0 = *(const uint4*)(we2t + (n0*16 + fn) * 64 + fk8);
        uint4 bw1 = *(const uint4*)(we2t + (n0*16 + fn) * 64 + 32 + fk8);
        const float bias = we_b2[n0 * 16 + fn];
        f32x4 q = {bias, bias, bias, bias};
        q = __builtin_amdgcn_mfma_f32_16x16x32_bf16(a0, __builtin_bit_cast(short8, bw0), q, 0, 0, 0);
        q = __builtin_amdgcn_mfma_f32_16x16x32_bf16(a1, __builtin_bit_cast(short8, bw1), q, 0, 0, 0);
        #pragma unroll
        for (int r2 = 0; r2 < 4; r2++) {
            const int m = mb + (lane >> 4) * 4 + r2;
            T[swzb(m * 128 + (n0*16 + fn) * 2) >> 1] = bf16rne(fast_tanh(q[r2]));
        }
    }

    // ---- phi_x: S = X2 @ Wx1 + b1; px = tanh(tanh(S) @ wx2 + b2) ----
    short8 c0, c1;
    {
        const int ba = swzb((mb + fn) * 128 + fk8 * 2);
        const int bb = swzb((mb + fn) * 128 + 64 + fk8 * 2);
        c0 = *(const short8*)(&T[ba >> 1]);
        c1 = *(const short8*)(&T[bb >> 1]);
    }
    float pxp[4] = {0.f, 0.f, 0.f, 0.f};
    #pragma unroll
    for (int n0 = 0; n0 < 4; n0++) {
        uint4 bw0 = *(const uint4*)(wx1t + (n0*16 + fn) * 64 + fk8);
        uint4 bw1 = *(const uint4*)(wx1t + (n0*16 + fn) * 64 + 32 + fk8);
        const float bias = wx_b1[n0 * 16 + fn];
        f32x4 q = {bias, bias, bias, bias};
        q = __builtin_amdgcn_mfma_f32_16x16x32_bf16(c0, __builtin_bit_cast(short8, bw0), q, 0, 0, 0);
        q = __builtin_amdgcn_mfma_f32_16x16x32_bf16(c1, __builtin_bit_cast(short8, bw1), q, 0, 0, 0);
        const float wqn = wx_w2[n0 * 16 + fn];
        #pragma unroll
        for (int r2 = 0; r2 < 4; r2++) pxp[r2] += fast_tanh(q[r2]) * wqn;
    }
    #pragma unroll
    for (int off = 1; off < 16; off <<= 1) {
        #pragma unroll
        for (int r2 = 0; r2 < 4; r2++) pxp[r2] += __shfl_xor(pxp[r2], off, 64);
    }
    if (fn == 0) {
        const float bx2 = wx_b2[0];
        #pragma unroll
        for (int r2 = 0; r2 < 4; r2++) {
            const int m = mb + (lane >> 4) * 4 + r2;
            pxS[m] = fast_tanh(pxp[r2] + bx2);
        }
    }
    __syncthreads();   // barrier 2: T(X2)/pxS complete for cross-wave read

    // ---- fused segment sum: wave w owns segments STARTING in [w*16, w*16+16) ----
    const int w16 = wv * 16;
    for (int s0 = w16; s0 < w16 + 16; s0++) {
        const int r0 = rS[s0];
        if (r0 < 0) continue;
        if (s0 > 0 && rS[s0 - 1] == r0) continue;   // not a segment start
        int s1 = s0 + 1;
        while (s1 < 64 && rS[s1] == r0) s1++;
        float msum = 0.0f, tsum = 0.0f;
        for (int t = s0; t < s1; t++) {
            msum += UB_LO((uint)T[swzb(t * 128 + lane * 2) >> 1]);
            if (lane < 3) tsum += dS[t][lane] * pxS[t];
        }
        atomicAdd(&miF[(size_t)r0 * 64 + lane], msum);
        if (lane < 3) atomicAdd(&aggF[(size_t)r0 * 3 + lane], tsum);
        if (lane == 3) atomicAdd(&cntF[r0], (float)(s1 - s0));
    }
}

// ---------------------------------------------- fused aggregation + node MLP ---
__global__ __launch_bounds__(256, 2)
void aggnode_kernel(const float* __restrict__ h, const float* __restrict__ x,
                    const float* __restrict__ vel,
                    const float* __restrict__ miF, const float* __restrict__ aggF,
                    const float* __restrict__ cntF,
                    const u16* __restrict__ wv1t, const float* __restrict__ wv_b1,
                    const float* __restrict__ wv_w2, const float* __restrict__ wv_b2,
                    const u16* __restrict__ wh1t, const float* __restrict__ wh_b1,
                    const u16* __restrict__ wh2t, const float* __restrict__ wh_b2,
                    float* __restrict__ out_h, float* __restrict__ out_x,
                    float* __restrict__ out_v, int N)
{
    __shared__ u16 Xh[4096];      // h tile, bf16 swizzled
    __shared__ u16 Xm[4096];      // mi tile, then reused for act tile
    __shared__ float aggM[64][3];
    __shared__ float pvS[64];

    const int tid = threadIdx.x, lane = tid & 63, wv = tid >> 6;
    const int nb = blockIdx.x * 64;
    const int el = tid >> 2, jg = tid & 3;
    const int fn = lane & 15, fk8 = (lane >> 4) * 8;

    // ---- stage h tile ----
    {
        uint pk[8];
        if (nb + el < N) {
            const float4* h4 = (const float4*)(h + (size_t)(nb + el) * 64 + jg * 16);
            #pragma unroll
            for (int q = 0; q < 4; q++) {
                float4 v = h4[q];
                pk[2*q]   = packbf_fast(v.x, v.y);
                pk[2*q+1] = packbf_fast(v.z, v.w);
            }
        } else {
            #pragma unroll
            for (int q = 0; q < 8; q++) pk[q] = 0;
        }
        const int b0 = swzb(el * 128 + jg * 32), b1 = swzb(el * 128 + jg * 32 + 16);
        *(uint4*)(&Xh[b0 >> 1]) = make_uint4(pk[0], pk[1], pk[2], pk[3]);
        *(uint4*)(&Xh[b1 >> 1]) = make_uint4(pk[4], pk[5], pk[6], pk[7]);
    }

    // ---- stage mi tile from miF (coalesced f32) + agg means ----
    for (int t = 0; t < 16; t++) {
        const int ln = wv * 16 + t;
        const int n = nb + ln;
        float val = 0.0f;
        if (n < N) val = miF[(size_t)n * 64 + lane];
        Xm[swzb(ln * 128 + lane * 2) >> 1] = bf16rne(val);
        if (lane < 3 && n < N) {
            const float cf = cntF[n];
            aggM[ln][lane] = aggF[(size_t)n * 3 + lane] / fmaxf(cf, 1.0f);
        }
    }
    __syncthreads();

    // ---- frag loads ----
    const int mb = wv * 16;
    short8 a0, a1, b0, b1;
    {
        const int ba = swzb((mb + fn) * 128 + fk8 * 2);
        const int bb = swzb((mb + fn) * 128 + 64 + fk8 * 2);
        a0 = *(const short8*)(&Xh[ba >> 1]);
        a1 = *(const short8*)(&Xh[bb >> 1]);
        b0 = *(const short8*)(&Xm[ba >> 1]);
        b1 = *(const short8*)(&Xm[bb >> 1]);
    }

    // ---- phi_v ----
    float pvp[4] = {0.f, 0.f, 0.f, 0.f};
    #pragma unroll
    for (int n0 = 0; n0 < 4; n0++) {
        uint4 bw0 = *(const uint4*)(wv1t + (n0*16 + fn) * 64 + fk8);
        uint4 bw1 = *(const uint4*)(wv1t + (n0*16 + fn) * 64 + 32 + fk8);
        const float bias = wv_b1[n0 * 16 + fn];
        f32x4 q = {bias, bias, bias, bias};
        q = __builtin_amdgcn_mfma_f32_16x16x32_bf16(a0, __builtin_bit_cast(short8, bw0), q, 0, 0, 0);
        q = __builtin_amdgcn_mfma_f32_16x16x32_bf16(a1, __builtin_bit_cast(short8, bw1), q, 0, 0, 0);
        const float wqn = wv_w2[n0 * 16 + fn];
        #pragma unroll
        for (int r2 = 0; r2 < 4; r2++) pvp[r2] += fast_tanh(q[r2]) * wqn;
    }
    #pragma unroll
    for (int off = 1; off < 16; off <<= 1) {
        #pragma unroll
        for (int r2 = 0; r2 < 4; r2++) pvp[r2] += __shfl_xor(pvp[r2], off, 64);
    }
    if (fn == 0) {
        const float bv2 = wv_b2[0];
        #pragma unroll
        for (int r2 = 0; r2 < 4; r2++) pvS[mb + (lane >> 4) * 4 + r2] = pvp[r2] + bv2;
    }
    __syncthreads();   // all frag loads done; Xm may now be overwritten

    // ---- phi_h layer 1 (K=128: [h | mi]) -> act tile (into Xm region) ----
    #pragma unroll
    for (int n0 = 0; n0 < 4; n0++) {
        const u16* base = wh1t + (n0*16 + fn) * 128;
        uint4 bw0 = *(const uint4*)(base + fk8);
        uint4 bw1 = *(const uint4*)(base + 32 + fk8);
        uint4 bw2 = *(const uint4*)(base + 64 + fk8);
        uint4 bw3 = *(const uint4*)(base + 96 + fk8);
        const float bias = wh_b1[n0 * 16 + fn];
        f32x4 q = {bias, bias, bias, bias};
        q = __builtin_amdgcn_mfma_f32_16x16x32_bf16(a0, __builtin_bit_cast(short8, bw0), q, 0, 0, 0);
        q = __builtin_amdgcn_mfma_f32_16x16x32_bf16(a1, __builtin_bit_cast(short8, bw1), q, 0, 0, 0);
        q = __builtin_amdgcn_mfma_f32_16x16x32_bf16(b0, __builtin_bit_cast(short8, bw2), q, 0, 0, 0);
        q = __builtin_amdgcn_mfma_f32_16x16x32_bf16(b1, __builtin_bit_cast(short8, bw3), q, 0, 0, 0);
        #pragma unroll
        for (int r2 = 0; r2 < 4; r2++) {
            const int m = mb + (lane >> 4) * 4 + r2;
            Xm[swzb(m * 128 + (n0*16 + fn) * 2) >> 1] = bf16rne(fast_tanh(q[r2]));
        }
    }
    __syncthreads();

    // ---- phi_h layer 2 -> out_h ----
    short8 c0, c1;
    {
        const int ba = swzb((mb + fn) * 128 + fk8 * 2);
        const int bb = swzb((mb + fn) * 128 + 64 + fk8 * 2);
        c0 = *(const short8*)(&Xm[ba >> 1]);
        c1 = *(const short8*)(&Xm[bb >> 1]);
    }
    #pragma unroll
    for (int n0 = 0; n0 < 4; n0++) {
        uint4 bw0 = *(const uint4*)(wh2t + (n0*16 + fn) * 64 + fk8);
        uint4 bw1 = *(const uint4*)(wh2t + (n0*16 + fn) * 64 + 32 + fk8);
        const float bias = wh_b2[n0 * 16 + fn];
        f32x4 q = {bias, bias, bias, bias};
        q = __builtin_amdgcn_mfma_f32_16x16x32_bf16(c0, __builtin_bit_cast(short8, bw0), q, 0, 0, 0);
        q = __builtin_amdgcn_mfma_f32_16x16x32_bf16(c1, __builtin_bit_cast(short8, bw1), q, 0, 0, 0);
        #pragma unroll
        for (int r2 = 0; r2 < 4; r2++) {
            const int m = mb + (lane >> 4) * 4 + r2;
            if (nb + m < N) out_h[(size_t)(nb + m) * 64 + n0 * 16 + fn] = q[r2];
        }
    }

    // ---- coordinate / velocity update ----
    if (tid < 64 && nb + tid < N) {
        const int n = nb + tid;
        const float pv = pvS[tid];
        #pragma unroll
        for (int d = 0; d < 3; d++) {
            const float am = aggM[tid][d];
            const float vn = vel[(size_t)n * 3 + d] * pv + am;
            out_v[(size_t)n * 3 + d] = vn;
            out_x[(size_t)n * 3 + d] = x[(size_t)n * 3 + d] + vn;
        }
    }
}

// ---------------------------------------------------------------- CSR build ---
// single-block chunked scan (r7-proven): hist -> offs/cursor
__global__ __launch_bounds__(1024)
void scan_kernel(const int* __restrict__ hist, int* __restrict__ offs,
                 int* __restrict__ cursor, int N) {
    const int tid = threadIdx.x;
    const int chunk = (N + 1023) / 1024;
    const int beg = tid * chunk;
    const int end = (beg + chunk < N) ? beg + chunk : N;

    int s = 0;
    for (int i = beg; i < end; i++) s += hist[i];

    __shared__ int wsum[16];
    const int lane = tid & 63, wid = tid >> 6;
    int inc = s;
    #pragma unroll
    for (int off = 1; off < 64; off <<= 1) {
        int t = __shfl_up(inc, off, 64);
        if (lane >= off) inc += t;
    }
    if (lane == 63) wsum[wid] = inc;
    __syncthreads();
    if (wid == 0 && lane < 16) {
        int v = wsum[lane];
        #pragma unroll
        for (int off = 1; off < 16; off <<= 1) {
            int t = __shfl_up(v, off, 64);
            if (lane >= off) v += t;
        }
        wsum[lane] = v;
    }
    __syncthreads();
    const int wbase = (wid > 0) ? wsum[wid - 1] : 0;
    int run = wbase + inc - s;
    for (int i = beg; i < end; i++) {
        cursor[i] = run;
        run += hist[i];
        offs[i + 1] = run;
    }
    if (tid == 0) offs[0] = 0;
}

// scatter: rec[slot] = [r, c, -, -, ea01, ea23, ea45, ea67]  (32B record)
__global__ void scatter_kernel(const int* __restrict__ rows, const int* __restrict__ cols,
                               const float* __restrict__ eattr,
                               int* __restrict__ cursor, uint* __restrict__ rec, int E) {
    int e = blockIdx.x * blockDim.x + threadIdx.x;
    if (e < E) {
        int r = rows[e];
        int p = atomicAdd(&cursor[r], 1);
        const float4* ea4 = (const float4*)(eattr + (size_t)e * 8);
        float4 u0 = ea4[0], u1 = ea4[1];
        *(int2*)(rec + (size_t)p * 8) = make_int2(r, cols[e]);
        *(uint4*)(rec + (size_t)p * 8 + 4) =
            make_uint4(packbf(u0.x, u0.y), packbf(u0.z, u0.w),
                       packbf(u1.x, u1.y), packbf(u1.z, u1.w));
    }
}

// ------------------------------------------- fallback kernels (atomic path) ---
template<int BLK>
__global__ __launch_bounds__(BLK)
void edge_atomic_kernel(const float* __restrict__ h, const float* __restrict__ x,
                 const float* __restrict__ eattr,
                 const int* __restrict__ rows, const int* __restrict__ cols,
                 const float* __restrict__ we_w1, const float* __restrict__ we_b1,
                 const float* __restrict__ we_w2, const float* __restrict__ we_b2,
                 const float* __restrict__ wx_w1, const float* __restrict__ wx_b1,
                 const float* __restrict__ wx_w2, const float* __restrict__ wx_b2,
                 float* __restrict__ agg, float* __restrict__ cnt, float* __restrict__ mi,
                 int E)
{
    __shared__ float act[64][BLK];
    const int tid = threadIdx.x;
    const int e = blockIdx.x * BLK + tid;
    if (e >= E) return;

    const int r = rows[e];
    const int c = cols[e];
    const float d0 = x[(size_t)r*3+0] - x[(size_t)c*3+0];
    const float d1 = x[(size_t)r*3+1] - x[(size_t)c*3+1];
    const float d2 = x[(size_t)r*3+2] - x[(size_t)c*3+2];
    const float rad = d0*d0 + d1*d1 + d2*d2;

    float A[64];
    #pragma unroll
    for (int j = 0; j < 64; j++) A[j] = we_b1[j];
    const float* hr = h + (size_t)r * 64;
    const float* hc = h + (size_t)c * 64;
    #pragma unroll 4
    for (int k = 0; k < 64; k++) {
        const float a0 = hr[k];
        const float a1 = hc[k];
        const float* w0 = we_w1 + k * 64;
        const float* w1 = we_w1 + (64 + k) * 64;
        #pragma unroll
        for (int j = 0; j < 64; j++) A[j] += a0 * w0[j] + a1 * w1[j];
    }
    {
        const float* w = we_w1 + 128 * 64;
        #pragma unroll
        for (int j = 0; j < 64; j++) A[j] += rad * w[j];
    }
    const float* ea = eattr + (size_t)e * 8;
    #pragma unroll
    for (int k = 0; k < 8; k++) {
        const float a = ea[k];
        const float* w = we_w1 + (129 + k) * 64;
        #pragma unroll
        for (int j = 0; j < 64; j++) A[j] += a * w[j];
    }
    #pragma unroll
    for (int j = 0; j < 64; j++) act[j][tid] = fast_tanh(A[j]);

    float B[64];
    #pragma unroll
    for (int j = 0; j < 64; j++) B[j] = we_b2[j];
    #pragma unroll 4
    for (int k = 0; k < 64; k++) {
        const float a = act[k][tid];
        const float* w = we_w2 + k * 64;
        #pragma unroll
        for (int j = 0; j < 64; j++) B[j] += a * w[j];
    }
    #pragma unroll
    for (int j = 0; j < 64; j++) act[j][tid] = fast_tanh(B[j]);

    #pragma unroll
    for (int j = 0; j < 64; j++) A[j] = wx_b1[j];
    #pragma unroll 4
    for (int k = 0; k < 64; k++) {
        const float a = act[k][tid];
        const float* w = wx_w1 + k * 64;
        #pragma unroll
        for (int j = 0; j < 64; j++) A[j] += a * w[j];
    }
    float px = wx_b2[0];
    #pragma unroll
    for (int j = 0; j < 64; j++) px += fast_tanh(A[j]) * wx_w2[j];
    px = fast_tanh(px);

    atomicAdd(&agg[(size_t)r*3+0], d0 * px);
    atomicAdd(&agg[(size_t)r*3+1], d1 * px);
    atomicAdd(&agg[(size_t)r*3+2], d2 * px);
    atomicAdd(&cnt[r], 1.0f);
    float* mir = mi + (size_t)r * 64;
    #pragma unroll
    for (int j = 0; j < 64; j++) atomicAdd(&mir[j], act[j][tid]);
}

template<int BLK>
__global__ __launch_bounds__(BLK, 2)
void node_fb_kernel(const float* __restrict__ h, const float* __restrict__ x,
                 const float* __restrict__ vel,
                 const float* __restrict__ wh_w1, const float* __restrict__ wh_b1,
                 const float* __restrict__ wh_w2, const float* __restrict__ wh_b2,
                 const float* __restrict__ wv_w1, const float* __restrict__ wv_b1,
                 const float* __restrict__ wv_w2, const float* __restrict__ wv_b2,
                 const float* __restrict__ agg, const float* __restrict__ cnt,
                 const float* __restrict__ mi,
                 float* __restrict__ out_h, float* __restrict__ out_x, float* __restrict__ out_v,
                 int N)
{
    const int n = blockIdx.x * BLK + threadIdx.x;
    if (n >= N) return;

    const float* hn = h + (size_t)n * 64;
    const float* mn = mi + (size_t)n * 64;

    float A[64];
    #pragma unroll
    for (int j = 0; j < 64; j++) A[j] = wv_b1[j];
    #pragma unroll
    for (int k = 0; k < 64; k++) {
        const float a = hn[k];
        const float* w = wv_w1 + k * 64;
        #pragma unroll
        for (int j = 0; j < 64; j++) A[j] += a * w[j];
    }
    float pv = wv_b2[0];
    #pragma unroll
    for (int j = 0; j < 64; j++) pv += fast_tanh(A[j]) * wv_w2[j];

    #pragma unroll
    for (int j = 0; j < 64; j++) A[j] = wh_b1[j];
    #pragma unroll
    for (int k = 0; k < 64; k++) {
        const float a0 = hn[k];
        const float a1 = mn[k];
        const float* w0 = wh_w1 + k * 64;
        const float* w1 = wh_w1 + (64 + k) * 64;
        #pragma unroll
        for (int j = 0; j < 64; j++) A[j] += a0 * w0[j] + a1 * w1[j];
    }
    #pragma unroll
    for (int j = 0; j < 64; j++) A[j] = fast_tanh(A[j]);

    float B[64];
    #pragma unroll
    for (int j = 0; j < 64; j++) B[j] = wh_b2[j];
    #pragma unroll
    for (int k = 0; k < 64; k++) {
        const float a = A[k];
        const float* w = wh_w2 + k * 64;
        #pragma unroll
        for (int j = 0; j < 64; j++) B[j] += a * w[j];
    }
    float* oh = out_h + (size_t)n * 64;
    #pragma unroll
    for (int j = 0; j < 64; j++) oh[j] = B[j];

    const float inv = 1.0f / fmaxf(cnt[n], 1.0f);
    #pragma unroll
    for (int d = 0; d < 3; d++) {
        const float am = agg[(size_t)n*3 + d] * inv;
        const float vn = vel[(size_t)n*3 + d] * pv + am;
        out_v[(size_t)n*3 + d] = vn;
        out_x[(size_t)n*3 + d] = x[(size_t)n*3 + d] + vn;
    }
}

// ------------------------------------------------------------------ launch ---
extern "C" void kernel_launch(void* const* d_in, const int* in_sizes, int n_in,
                              void* d_out, int out_size, void* d_ws, size_t ws_size,
                              hipStream_t stream) {
    const float* h      = (const float*)d_in[0];
    const float* x      = (const float*)d_in[1];
    const float* vel    = (const float*)d_in[2];
    const float* eattr  = (const float*)d_in[3];
    const float* we_w1  = (const float*)d_in[4];
    const float* we_b1  = (const float*)d_in[5];
    const float* we_w2  = (const float*)d_in[6];
    const float* we_b2  = (const float*)d_in[7];
    const float* wx_w1  = (const float*)d_in[8];
    const float* wx_b1  = (const float*)d_in[9];
    const float* wx_w2  = (const float*)d_in[10];
    const float* wx_b2  = (const float*)d_in[11];
    const float* wh_w1  = (const float*)d_in[12];
    const float* wh_b1  = (const float*)d_in[13];
    const float* wh_w2  = (const float*)d_in[14];
    const float* wh_b2  = (const float*)d_in[15];
    const float* wv_w1  = (const float*)d_in[16];
    const float* wv_b1  = (const float*)d_in[17];
    const float* wv_w2  = (const float*)d_in[18];
    const float* wv_b2  = (const float*)d_in[19];
    const int*   ar     = (const int*)d_in[20];

    const int N = in_sizes[0] / 64;
    const int E = in_sizes[20] / 2;
    const int* rows = ar;
    const int* cols = ar + E;

    float* out_h = (float*)d_out;            // N*64 (HrB/HcB bf16 scratch first)
    float* out_x = out_h + (size_t)N * 64;   // N*3
    float* out_v = out_x + (size_t)N * 3;    // N*3

    u16* HrB = (u16*)d_out;
    u16* HcB = HrB + (size_t)N * 64;

    // --- workspace layout: ~90 MB. miF..hist contiguous -> ONE memset ---
    char* p = (char*)d_ws;
    float* miF  = (float*)p; p += (size_t)N * 64 * sizeof(float);
    float* aggF = (float*)p; p += (size_t)N * 3 * sizeof(float);
    float* cntF = (float*)p; p += (size_t)N * sizeof(float);
    int*  hist  = (int*)p;   p += (size_t)N * sizeof(int);
    const size_t zero_bytes = (size_t)(p - (char*)d_ws);
    int*  offs  = (int*)p;   p += (size_t)(N + 1) * sizeof(int);
    int*  cursor= (int*)p;   p += (size_t)N * sizeof(int);
    p = (char*)(((uintptr_t)p + 31) & ~(uintptr_t)31);
    uint* rec   = (uint*)p;  p += (size_t)E * 8 * sizeof(uint);   // 32B/slot
    p = (char*)(((uintptr_t)p + 63) & ~(uintptr_t)63);
    u16*  we1t = (u16*)p;   p += 64 * 128 * sizeof(u16);
    u16*  we2t = (u16*)p;   p += 64 * 64 * sizeof(u16);
    u16*  wx1t = (u16*)p;   p += 64 * 64 * sizeof(u16);
    u16*  wv1t = (u16*)p;   p += 64 * 64 * sizeof(u16);
    u16*  wh1t = (u16*)p;   p += 64 * 128 * sizeof(u16);
    u16*  wh2t = (u16*)p;   p += 64 * 64 * sizeof(u16);
    u16*  wert = (u16*)p;   p += 64 * 32 * sizeof(u16);
    const size_t needed = (size_t)(p - (char*)d_ws);

    if (ws_size >= needed) {
        hipMemsetAsync(d_ws, 0, zero_bytes, stream);
        wprep_hist_kernel<<<32 + (E + 255) / 256, 256, 0, stream>>>(
            we_w1, we_w2, wx_w1, wv_w1, wh_w1, wh_w2,
            we1t, we2t, wx1t, wv1t, wh1t, wh2t, wert, rows, hist, E);
        scan_kernel<<<1, 1024, 0, stream>>>(hist, offs, cursor, N);
        scatter_kernel<<<(E + 255) / 256, 256, 0, stream>>>(rows, cols, eattr, cursor, rec, E);

        pre_mfma_kernel<<<(N + 63) / 64, 256, 0, stream>>>(h, we_b1, we1t, HrB, HcB, N);

        edge_mfma_kernel<<<(E + 63) / 64, 256, 0, stream>>>(
            x, rec, HrB, HcB,
            wert, we2t, we_b2, wx1t, wx_b1, wx_w2, wx_b2,
            miF, aggF, cntF, E);

        aggnode_kernel<<<(N + 63) / 64, 256, 0, stream>>>(
            h, x, vel, miF, aggF, cntF,
            wv1t, wv_b1, wv_w2, wv_b2,
            wh1t, wh_b1, wh2t, wh_b2,
            out_h, out_x, out_v, N);
    } else {
        // --- fallback: atomic path ---
        float* agg2 = (float*)d_ws;               // N*3
        float* cnt2 = agg2 + (size_t)N * 3;       // N
        float* mi2  = cnt2 + N;                   // N*64
        hipMemsetAsync(d_ws, 0, (size_t)N * 68 * sizeof(float), stream);

        edge_atomic_kernel<128><<<(E + 127) / 128, 128, 0, stream>>>(
            h, x, eattr, rows, cols,
            we_w1, we_b1, we_w2, we_b2,
            wx_w1, wx_b1, wx_w2, wx_b2,
            agg2, cnt2, mi2, E);

        node_fb_kernel<128><<<(N + 127) / 128, 128, 0, stream>>>(
            h, x, vel,
            wh_w1, wh_b1, wh_w2, wh_b2,
            wv_w1, wv_b1, wv_w2, wv_b2,
            agg2, cnt2, mi2, out_h, out_x, out_v, N);
    }
}

// Round 12
// 550.359 us; speedup vs baseline: 1.3097x; 1.3097x over previous
//
#include <hip/hip_runtime.h>

// EGNN layer (CamadaEquivariante), round 12 = round 10 structure (proven 552us)
//  + occupancy bumps on pre_mfma/aggnode (launch_bounds 256,4).
// r11's sequential-ea experiment REVERTED: moving the random ea gather into
// scatter cost +190us in CSR build to save 20us in edge.
//  - edge_mfma: single in-place LDS tile T (Xp -> X1 -> X2), 2 barriers,
//    radS reuse, rc int2 loads, occupancy 8 blocks/CU.
//  - scatter writes rc=(r,c) int2 + perm (12B random).
//  - CSR: hist -> 3-kernel parallel scan -> scatter.
// ws ~= 48 MB. Fallback to atomic path if ws too small.

typedef unsigned int uint;
typedef unsigned short u16;
typedef __attribute__((ext_vector_type(8))) short short8;
typedef __attribute__((ext_vector_type(4))) float f32x4;

#define UB_LO(u) __uint_as_float((u) << 16)
#define UB_HI(u) __uint_as_float((u) & 0xffff0000u)

__device__ __forceinline__ float fast_tanh(float x) {
    float e = __expf(2.0f * x);
    return 1.0f - 2.0f * __builtin_amdgcn_rcpf(e + 1.0f);
}
__device__ __forceinline__ u16 bf16rne(float f) {
    uint u = __float_as_uint(f);
    return (u16)((u + 0x7fffu + ((u >> 16) & 1u)) >> 16);
}
__device__ __forceinline__ uint packbf(float a, float b) {
    return (uint)bf16rne(a) | ((uint)bf16rne(b) << 16);
}
// 1-inst truncating bf16x2 pack: lo16 = hi16(a), hi16 = hi16(b)
__device__ __forceinline__ uint packbf_fast(float a, float b) {
    return __builtin_amdgcn_perm(__float_as_uint(b), __float_as_uint(a), 0x07060302u);
}
__device__ __forceinline__ u16 trunc16(float f) {
    return (u16)(__float_as_uint(f) >> 16);
}
// XOR-swizzle within a [64][64]-bf16 (128B-row) LDS tile: byte ^= ((row&7)<<4)
__device__ __forceinline__ int swzb(int b) { return b ^ ((b >> 3) & 0x70); }

// ------------------------------------------------- weight transpose (bf16) ---
__global__ void wprep_kernel(const float* __restrict__ we_w1, const float* __restrict__ we_w2,
                             const float* __restrict__ wx_w1, const float* __restrict__ wv_w1,
                             const float* __restrict__ wh_w1, const float* __restrict__ wh_w2,
                             u16* __restrict__ we1t, u16* __restrict__ we2t,
                             u16* __restrict__ wx1t, u16* __restrict__ wv1t,
                             u16* __restrict__ wh1t, u16* __restrict__ wh2t,
                             u16* __restrict__ wert) {
    int t = blockIdx.x * 256 + threadIdx.x;
    if (t < 8192) {
        int j = t >> 7, k = t & 127;
        we1t[t] = bf16rne(we_w1[k * 64 + j]);
        wh1t[t] = bf16rne(wh_w1[k * 64 + j]);
    }
    if (t < 4096) {
        int n = t >> 6, k = t & 63;
        we2t[t] = bf16rne(we_w2[k * 64 + n]);
        wx1t[t] = bf16rne(wx_w1[k * 64 + n]);
        wv1t[t] = bf16rne(wv_w1[k * 64 + n]);
        wh2t[t] = bf16rne(wh_w2[k * 64 + n]);
    }
    if (t < 2048) {          // wert[n][k], k=0 -> rad row (128), k=1..8 -> rows 129..136
        int n = t >> 5, k = t & 31;
        float v = 0.0f;
        if (k == 0) v = we_w1[128 * 64 + n];
        else if (k <= 8) v = we_w1[(128 + k) * 64 + n];
        wert[t] = bf16rne(v);
    }
}

// --------------------------------------------------------- pre MFMA kernel ---
__global__ __launch_bounds__(256, 4)
void pre_mfma_kernel(const float* __restrict__ h, const float* __restrict__ we_b1,
                     const u16* __restrict__ we1t,
                     u16* __restrict__ HrB, u16* __restrict__ HcB, int N)
{
    __shared__ u16 X1[4096];
    __shared__ u16 X2[4096];
    const int tid = threadIdx.x, lane = tid & 63, wv = tid >> 6;
    const int nb = blockIdx.x * 64;
    const int el = tid >> 2, jg = tid & 3;
    const int fn = lane & 15, fk8 = (lane >> 4) * 8;

    {
        uint pk[8];
        if (nb + el < N) {
            const float4* h4 = (const float4*)(h + (size_t)(nb + el) * 64 + jg * 16);
            #pragma unroll
            for (int q = 0; q < 4; q++) {
                float4 v = h4[q];
                pk[2*q]   = packbf_fast(v.x, v.y);
                pk[2*q+1] = packbf_fast(v.z, v.w);
            }
        } else {
            #pragma unroll
            for (int q = 0; q < 8; q++) pk[q] = 0;
        }
        const int b0 = swzb(el * 128 + jg * 32), b1 = swzb(el * 128 + jg * 32 + 16);
        *(uint4*)(&X1[b0 >> 1]) = make_uint4(pk[0], pk[1], pk[2], pk[3]);
        *(uint4*)(&X1[b1 >> 1]) = make_uint4(pk[4], pk[5], pk[6], pk[7]);
    }
    __syncthreads();

    const int mb = wv * 16;
    short8 a0, a1;
    {
        const int ba = swzb((mb + fn) * 128 + fk8 * 2);
        const int bb = swzb((mb + fn) * 128 + 64 + fk8 * 2);
        a0 = *(const short8*)(&X1[ba >> 1]);
        a1 = *(const short8*)(&X1[bb >> 1]);
    }
    // Hr = h @ We1[0:64] + b1
    #pragma unroll
    for (int n0 = 0; n0 < 4; n0++) {
        uint4 bw0 = *(const uint4*)(we1t + (n0*16 + fn) * 128 + fk8);
        uint4 bw1 = *(const uint4*)(we1t + (n0*16 + fn) * 128 + 32 + fk8);
        const float bias = we_b1[n0 * 16 + fn];
        f32x4 q = {bias, bias, bias, bias};
        q = __builtin_amdgcn_mfma_f32_16x16x32_bf16(a0, __builtin_bit_cast(short8, bw0), q, 0, 0, 0);
        q = __builtin_amdgcn_mfma_f32_16x16x32_bf16(a1, __builtin_bit_cast(short8, bw1), q, 0, 0, 0);
        #pragma unroll
        for (int r2 = 0; r2 < 4; r2++) {
            const int m = mb + (lane >> 4) * 4 + r2;
            X2[swzb(m * 128 + (n0*16 + fn) * 2) >> 1] = bf16rne(q[r2]);
        }
    }
    __syncthreads();
    if (nb + el < N) {
        const int b0 = swzb(el * 128 + jg * 32), b1 = swzb(el * 128 + jg * 32 + 16);
        uint4 v0 = *(const uint4*)(&X2[b0 >> 1]);
        uint4 v1 = *(const uint4*)(&X2[b1 >> 1]);
        u16* o = HrB + (size_t)(nb + el) * 64 + jg * 16;
        *(uint4*)o = v0; *(uint4*)(o + 8) = v1;
    }
    __syncthreads();
    // Hc = h @ We1[64:128]
    #pragma unroll
    for (int n0 = 0; n0 < 4; n0++) {
        uint4 bw0 = *(const uint4*)(we1t + (n0*16 + fn) * 128 + 64 + fk8);
        uint4 bw1 = *(const uint4*)(we1t + (n0*16 + fn) * 128 + 96 + fk8);
        f32x4 q = {0.f, 0.f, 0.f, 0.f};
        q = __builtin_amdgcn_mfma_f32_16x16x32_bf16(a0, __builtin_bit_cast(short8, bw0), q, 0, 0, 0);
        q = __builtin_amdgcn_mfma_f32_16x16x32_bf16(a1, __builtin_bit_cast(short8, bw1), q, 0, 0, 0);
        #pragma unroll
        for (int r2 = 0; r2 < 4; r2++) {
            const int m = mb + (lane >> 4) * 4 + r2;
            X2[swzb(m * 128 + (n0*16 + fn) * 2) >> 1] = bf16rne(q[r2]);
        }
    }
    __syncthreads();
    if (nb + el < N) {
        const int b0 = swzb(el * 128 + jg * 32), b1 = swzb(el * 128 + jg * 32 + 16);
        uint4 v0 = *(const uint4*)(&X2[b0 >> 1]);
        uint4 v1 = *(const uint4*)(&X2[b1 >> 1]);
        u16* o = HcB + (size_t)(nb + el) * 64 + jg * 16;
        *(uint4*)o = v0; *(uint4*)(o + 8) = v1;
    }
}

// --------------------------------------------------------- edge MFMA kernel ---
// Slot order + XCD-chunked swizzle. Single in-place tile T: Xp -> X1 -> X2.
// Band ownership: each wave's MFMA frag reads/writes touch only rows
// [wv*16, wv*16+16); cross-wave accesses only at phase A (write) and
// segment-sum (read) -> exactly 2 barriers.
__global__ __launch_bounds__(256, 8)
void edge_mfma_kernel(const float* __restrict__ x, const float* __restrict__ eattr,
                      const int* __restrict__ perm, const int2* __restrict__ rc,
                      const u16* __restrict__ HrB, const u16* __restrict__ HcB,
                      const u16* __restrict__ wert,
                      const u16* __restrict__ we2t, const float* __restrict__ we_b2,
                      const u16* __restrict__ wx1t, const float* __restrict__ wx_b1,
                      const float* __restrict__ wx_w2, const float* __restrict__ wx_b2,
                      float* __restrict__ miF, float* __restrict__ aggF,
                      float* __restrict__ cntF, int E)
{
    __shared__ u16 T[4096];        // Xp -> X1 -> X2 (in place)
    __shared__ float dS[64][3];
    __shared__ float pxS[64];
    __shared__ float radS[64];
    __shared__ int rS[64];

    const int tid = threadIdx.x, lane = tid & 63, wv = tid >> 6;
    int bid = blockIdx.x;
    const int nwg = gridDim.x;
    if ((nwg & 7) == 0) bid = (bid & 7) * (nwg >> 3) + (bid >> 3);  // XCD-chunked
    const int sb = bid * 64;
    const int fn = lane & 15, fk8 = (lane >> 4) * 8;
    const int el = tid >> 2, jg = tid & 3;
    const int s = sb + el;
    const int mb = wv * 16;

    // ---- phase A: T = Hr[r] + Hc[c] (bf16); dS/radS/rS ----
    {
        int r = -1, c = 0;
        if (s < E) { int2 p2 = rc[s]; r = p2.x; c = p2.y; }
        if (jg == 0) rS[el] = r;
        uint pk[8];
        if (s < E) {
            if (jg == 0) {
                const float d0 = x[(size_t)r*3+0] - x[(size_t)c*3+0];
                const float d1 = x[(size_t)r*3+1] - x[(size_t)c*3+1];
                const float d2 = x[(size_t)r*3+2] - x[(size_t)c*3+2];
                dS[el][0] = d0; dS[el][1] = d1; dS[el][2] = d2;
                radS[el] = d0*d0 + d1*d1 + d2*d2;
            }
            uint4 ra = *(const uint4*)(HrB + (size_t)r * 64 + jg * 16);
            uint4 rb = *(const uint4*)(HrB + (size_t)r * 64 + jg * 16 + 8);
            uint4 ca = *(const uint4*)(HcB + (size_t)c * 64 + jg * 16);
            uint4 cb = *(const uint4*)(HcB + (size_t)c * 64 + jg * 16 + 8);
            uint rw[8] = {ra.x, ra.y, ra.z, ra.w, rb.x, rb.y, rb.z, rb.w};
            uint cw[8] = {ca.x, ca.y, ca.z, ca.w, cb.x, cb.y, cb.z, cb.w};
            #pragma unroll
            for (int q = 0; q < 8; q++) {
                const float lo = UB_LO(rw[q]) + UB_LO(cw[q]);
                const float hi = UB_HI(rw[q]) + UB_HI(cw[q]);
                pk[q] = packbf_fast(lo, hi);
            }
        } else {
            #pragma unroll
            for (int q = 0; q < 8; q++) pk[q] = 0;
        }
        const int b0 = swzb(el * 128 + jg * 32), b1 = swzb(el * 128 + jg * 32 + 16);
        *(uint4*)(&T[b0 >> 1]) = make_uint4(pk[0], pk[1], pk[2], pk[3]);
        *(uint4*)(&T[b1 >> 1]) = make_uint4(pk[4], pk[5], pk[6], pk[7]);
    }
    __syncthreads();   // barrier 1: T(Xp)/dS/radS/rS visible

    // ---- ea/rad A-frag: lane fn = edge (mb+fn), k-chunk = lane>>4 ----
    uint ae[4] = {0, 0, 0, 0};
    {
        const int kc = lane >> 4;
        const int s2 = sb + mb + fn;
        if (kc < 2 && s2 < E) {
            const int e2 = perm[s2];
            const float4* ea4 = (const float4*)(eattr + (size_t)e2 * 8);
            if (kc == 0) {
                float4 u0 = ea4[0], u1 = ea4[1];
                const float rad = radS[mb + fn];
                ae[0] = packbf_fast(rad,  u0.x);   // k0=rad, k1=ea0
                ae[1] = packbf_fast(u0.y, u0.z);   // ea1, ea2
                ae[2] = packbf_fast(u0.w, u1.x);   // ea3, ea4
                ae[3] = packbf_fast(u1.y, u1.z);   // ea5, ea6
            } else {
                float4 u1 = ea4[1];
                ae[0] = packbf_fast(u1.w, 0.0f);   // k8=ea7
            }
        }
    }
    const short8 a_e = __builtin_bit_cast(short8, *(uint4*)ae);

    // ---- layer 1 (in place): q = MFMA(ea, wert); T = tanh(q + T) ----
    #pragma unroll
    for (int n0 = 0; n0 < 4; n0++) {
        uint4 bw = *(const uint4*)(wert + (n0*16 + fn) * 32 + fk8);
        f32x4 q = {0.f, 0.f, 0.f, 0.f};
        q = __builtin_amdgcn_mfma_f32_16x16x32_bf16(a_e, __builtin_bit_cast(short8, bw), q, 0, 0, 0);
        #pragma unroll
        for (int r2 = 0; r2 < 4; r2++) {
            const int idx = swzb((mb + (lane >> 4) * 4 + r2) * 128 + (n0*16 + fn) * 2) >> 1;
            const float pre = q[r2] + UB_LO((uint)T[idx]);
            T[idx] = trunc16(fast_tanh(pre));
        }
    }

    // ---- layer 2 (in place): read own-band frags, write X2 over X1 ----
    short8 a0, a1;
    {
        const int ba = swzb((mb + fn) * 128 + fk8 * 2);
        const int bb = swzb((mb + fn) * 128 + 64 + fk8 * 2);
        a0 = *(const short8*)(&T[ba >> 1]);
        a1 = *(const short8*)(&T[bb >> 1]);
    }
    #pragma unroll
    for (int n0 = 0; n0 < 4; n0++) {
        uint4 bw0 = *(const uint4*)(we2t + (n0*16 + fn) * 64 + fk8);
        uint4 bw1 = *(const uint4*)(we2t + (n0*16 + fn) * 64 + 32 + fk8);
        const float bias = we_b2[n0 * 16 + fn];
        f32x4 q = {bias, bias, bias, bias};
        q = __builtin_amdgcn_mfma_f32_16x16x32_bf16(a0, __builtin_bit_cast(short8, bw0), q, 0, 0, 0);
        q = __builtin_amdgcn_mfma_f32_16x16x32_bf16(a1, __builtin_bit_cast(short8, bw1), q, 0, 0, 0);
        #pragma unroll
        for (int r2 = 0; r2 < 4; r2++) {
            const int m = mb + (lane >> 4) * 4 + r2;
            T[swzb(m * 128 + (n0*16 + fn) * 2) >> 1] = bf16rne(fast_tanh(q[r2]));
        }
    }

    // ---- phi_x: S = X2 @ Wx1 + b1; px = tanh(tanh(S) @ wx2 + b2) ----
    short8 c0, c1;
    {
        const int ba = swzb((mb + fn) * 128 + fk8 * 2);
        const int bb = swzb((mb + fn) * 128 + 64 + fk8 * 2);
        c0 = *(const short8*)(&T[ba >> 1]);
        c1 = *(const short8*)(&T[bb >> 1]);
    }
    float pxp[4] = {0.f, 0.f, 0.f, 0.f};
    #pragma unroll
    for (int n0 = 0; n0 < 4; n0++) {
        uint4 bw0 = *(const uint4*)(wx1t + (n0*16 + fn) * 64 + fk8);
        uint4 bw1 = *(const uint4*)(wx1t + (n0*16 + fn) * 64 + 32 + fk8);
        const float bias = wx_b1[n0 * 16 + fn];
        f32x4 q = {bias, bias, bias, bias};
        q = __builtin_amdgcn_mfma_f32_16x16x32_bf16(c0, __builtin_bit_cast(short8, bw0), q, 0, 0, 0);
        q = __builtin_amdgcn_mfma_f32_16x16x32_bf16(c1, __builtin_bit_cast(short8, bw1), q, 0, 0, 0);
        const float wqn = wx_w2[n0 * 16 + fn];
        #pragma unroll
        for (int r2 = 0; r2 < 4; r2++) pxp[r2] += fast_tanh(q[r2]) * wqn;
    }
    #pragma unroll
    for (int off = 1; off < 16; off <<= 1) {
        #pragma unroll
        for (int r2 = 0; r2 < 4; r2++) pxp[r2] += __shfl_xor(pxp[r2], off, 64);
    }
    if (fn == 0) {
        const float bx2 = wx_b2[0];
        #pragma unroll
        for (int r2 = 0; r2 < 4; r2++) {
            const int m = mb + (lane >> 4) * 4 + r2;
            pxS[m] = fast_tanh(pxp[r2] + bx2);
        }
    }
    __syncthreads();   // barrier 2: T(X2)/pxS complete for cross-wave read

    // ---- fused segment sum: wave w owns segments STARTING in [w*16, w*16+16) ----
    const int w16 = wv * 16;
    for (int s0 = w16; s0 < w16 + 16; s0++) {
        const int r0 = rS[s0];
        if (r0 < 0) continue;
        if (s0 > 0 && rS[s0 - 1] == r0) continue;   // not a segment start
        int s1 = s0 + 1;
        while (s1 < 64 && rS[s1] == r0) s1++;
        float msum = 0.0f, tsum = 0.0f;
        for (int t = s0; t < s1; t++) {
            msum += UB_LO((uint)T[swzb(t * 128 + lane * 2) >> 1]);
            if (lane < 3) tsum += dS[t][lane] * pxS[t];
        }
        atomicAdd(&miF[(size_t)r0 * 64 + lane], msum);
        if (lane < 3) atomicAdd(&aggF[(size_t)r0 * 3 + lane], tsum);
        if (lane == 3) atomicAdd(&cntF[r0], (float)(s1 - s0));
    }
}

// ---------------------------------------------- fused aggregation + node MLP ---
__global__ __launch_bounds__(256, 4)
void aggnode_kernel(const float* __restrict__ h, const float* __restrict__ x,
                    const float* __restrict__ vel,
                    const float* __restrict__ miF, const float* __restrict__ aggF,
                    const float* __restrict__ cntF,
                    const u16* __restrict__ wv1t, const float* __restrict__ wv_b1,
                    const float* __restrict__ wv_w2, const float* __restrict__ wv_b2,
                    const u16* __restrict__ wh1t, const float* __restrict__ wh_b1,
                    const u16* __restrict__ wh2t, const float* __restrict__ wh_b2,
                    float* __restrict__ out_h, float* __restrict__ out_x,
                    float* __restrict__ out_v, int N)
{
    __shared__ u16 Xh[4096];      // h tile, bf16 swizzled
    __shared__ u16 Xm[4096];      // mi tile, then reused for act tile
    __shared__ float aggM[64][3];
    __shared__ float pvS[64];

    const int tid = threadIdx.x, lane = tid & 63, wv = tid >> 6;
    const int nb = blockIdx.x * 64;
    const int el = tid >> 2, jg = tid & 3;
    const int fn = lane & 15, fk8 = (lane >> 4) * 8;

    // ---- stage h tile ----
    {
        uint pk[8];
        if (nb + el < N) {
            const float4* h4 = (const float4*)(h + (size_t)(nb + el) * 64 + jg * 16);
            #pragma unroll
            for (int q = 0; q < 4; q++) {
                float4 v = h4[q];
                pk[2*q]   = packbf_fast(v.x, v.y);
                pk[2*q+1] = packbf_fast(v.z, v.w);
            }
        } else {
            #pragma unroll
            for (int q = 0; q < 8; q++) pk[q] = 0;
        }
        const int b0 = swzb(el * 128 + jg * 32), b1 = swzb(el * 128 + jg * 32 + 16);
        *(uint4*)(&Xh[b0 >> 1]) = make_uint4(pk[0], pk[1], pk[2], pk[3]);
        *(uint4*)(&Xh[b1 >> 1]) = make_uint4(pk[4], pk[5], pk[6], pk[7]);
    }

    // ---- stage mi tile from miF (coalesced f32) + agg means ----
    for (int t = 0; t < 16; t++) {
        const int ln = wv * 16 + t;
        const int n = nb + ln;
        float val = 0.0f;
        if (n < N) val = miF[(size_t)n * 64 + lane];
        Xm[swzb(ln * 128 + lane * 2) >> 1] = bf16rne(val);
        if (lane < 3 && n < N) {
            const float cf = cntF[n];
            aggM[ln][lane] = aggF[(size_t)n * 3 + lane] / fmaxf(cf, 1.0f);
        }
    }
    __syncthreads();

    // ---- frag loads ----
    const int mb = wv * 16;
    short8 a0, a1, b0, b1;
    {
        const int ba = swzb((mb + fn) * 128 + fk8 * 2);
        const int bb = swzb((mb + fn) * 128 + 64 + fk8 * 2);
        a0 = *(const short8*)(&Xh[ba >> 1]);
        a1 = *(const short8*)(&Xh[bb >> 1]);
        b0 = *(const short8*)(&Xm[ba >> 1]);
        b1 = *(const short8*)(&Xm[bb >> 1]);
    }

    // ---- phi_v ----
    float pvp[4] = {0.f, 0.f, 0.f, 0.f};
    #pragma unroll
    for (int n0 = 0; n0 < 4; n0++) {
        uint4 bw0 = *(const uint4*)(wv1t + (n0*16 + fn) * 64 + fk8);
        uint4 bw1 = *(const uint4*)(wv1t + (n0*16 + fn) * 64 + 32 + fk8);
        const float bias = wv_b1[n0 * 16 + fn];
        f32x4 q = {bias, bias, bias, bias};
        q = __builtin_amdgcn_mfma_f32_16x16x32_bf16(a0, __builtin_bit_cast(short8, bw0), q, 0, 0, 0);
        q = __builtin_amdgcn_mfma_f32_16x16x32_bf16(a1, __builtin_bit_cast(short8, bw1), q, 0, 0, 0);
        const float wqn = wv_w2[n0 * 16 + fn];
        #pragma unroll
        for (int r2 = 0; r2 < 4; r2++) pvp[r2] += fast_tanh(q[r2]) * wqn;
    }
    #pragma unroll
    for (int off = 1; off < 16; off <<= 1) {
        #pragma unroll
        for (int r2 = 0; r2 < 4; r2++) pvp[r2] += __shfl_xor(pvp[r2], off, 64);
    }
    if (fn == 0) {
        const float bv2 = wv_b2[0];
        #pragma unroll
        for (int r2 = 0; r2 < 4; r2++) pvS[mb + (lane >> 4) * 4 + r2] = pvp[r2] + bv2;
    }
    __syncthreads();   // all frag loads done; Xm may now be overwritten

    // ---- phi_h layer 1 (K=128: [h | mi]) -> act tile (into Xm region) ----
    #pragma unroll
    for (int n0 = 0; n0 < 4; n0++) {
        const u16* base = wh1t + (n0*16 + fn) * 128;
        uint4 bw0 = *(const uint4*)(base + fk8);
        uint4 bw1 = *(const uint4*)(base + 32 + fk8);
        uint4 bw2 = *(const uint4*)(base + 64 + fk8);
        uint4 bw3 = *(const uint4*)(base + 96 + fk8);
        const float bias = wh_b1[n0 * 16 + fn];
        f32x4 q = {bias, bias, bias, bias};
        q = __builtin_amdgcn_mfma_f32_16x16x32_bf16(a0, __builtin_bit_cast(short8, bw0), q, 0, 0, 0);
        q = __builtin_amdgcn_mfma_f32_16x16x32_bf16(a1, __builtin_bit_cast(short8, bw1), q, 0, 0, 0);
        q = __builtin_amdgcn_mfma_f32_16x16x32_bf16(b0, __builtin_bit_cast(short8, bw2), q, 0, 0, 0);
        q = __builtin_amdgcn_mfma_f32_16x16x32_bf16(b1, __builtin_bit_cast(short8, bw3), q, 0, 0, 0);
        #pragma unroll
        for (int r2 = 0; r2 < 4; r2++) {
            const int m = mb + (lane >> 4) * 4 + r2;
            Xm[swzb(m * 128 + (n0*16 + fn) * 2) >> 1] = bf16rne(fast_tanh(q[r2]));
        }
    }
    __syncthreads();

    // ---- phi_h layer 2 -> out_h ----
    short8 c0, c1;
    {
        const int ba = swzb((mb + fn) * 128 + fk8 * 2);
        const int bb = swzb((mb + fn) * 128 + 64 + fk8 * 2);
        c0 = *(const short8*)(&Xm[ba >> 1]);
        c1 = *(const short8*)(&Xm[bb >> 1]);
    }
    #pragma unroll
    for (int n0 = 0; n0 < 4; n0++) {
        uint4 bw0 = *(const uint4*)(wh2t + (n0*16 + fn) * 64 + fk8);
        uint4 bw1 = *(const uint4*)(wh2t + (n0*16 + fn) * 64 + 32 + fk8);
        const float bias = wh_b2[n0 * 16 + fn];
        f32x4 q = {bias, bias, bias, bias};
        q = __builtin_amdgcn_mfma_f32_16x16x32_bf16(c0, __builtin_bit_cast(short8, bw0), q, 0, 0, 0);
        q = __builtin_amdgcn_mfma_f32_16x16x32_bf16(c1, __builtin_bit_cast(short8, bw1), q, 0, 0, 0);
        #pragma unroll
        for (int r2 = 0; r2 < 4; r2++) {
            const int m = mb + (lane >> 4) * 4 + r2;
            if (nb + m < N) out_h[(size_t)(nb + m) * 64 + n0 * 16 + fn] = q[r2];
        }
    }

    // ---- coordinate / velocity update ----
    if (tid < 64 && nb + tid < N) {
        const int n = nb + tid;
        const float pv = pvS[tid];
        #pragma unroll
        for (int d = 0; d < 3; d++) {
            const float am = aggM[tid][d];
            const float vn = vel[(size_t)n * 3 + d] * pv + am;
            out_v[(size_t)n * 3 + d] = vn;
            out_x[(size_t)n * 3 + d] = x[(size_t)n * 3 + d] + vn;
        }
    }
}

// ---------------------------------------------------------------- CSR build ---
__global__ void hist_kernel(const int* __restrict__ rows, int* __restrict__ hist, int E) {
    int e = blockIdx.x * blockDim.x + threadIdx.x;
    if (e < E) atomicAdd(&hist[rows[e]], 1);
}

__global__ __launch_bounds__(256)
void scan1_kernel(const int* __restrict__ hist, int* __restrict__ bsum, int N) {
    const int t = threadIdx.x, b = blockIdx.x;
    const int base = b * 1024 + t * 4;
    int s = 0;
    #pragma unroll
    for (int q = 0; q < 4; q++) s += (base + q < N) ? hist[base + q] : 0;
    #pragma unroll
    for (int off = 1; off < 64; off <<= 1) s += __shfl_xor(s, off, 64);
    __shared__ int ws[4];
    if ((t & 63) == 0) ws[t >> 6] = s;
    __syncthreads();
    if (t == 0) bsum[b] = ws[0] + ws[1] + ws[2] + ws[3];
}

__global__ __launch_bounds__(256)
void scan2_kernel(int* __restrict__ bsum, int nb) {
    __shared__ int buf[1024];
    const int t = threadIdx.x;
    for (int i = t; i < nb; i += 256) buf[i] = bsum[i];
    __syncthreads();
    if (t == 0) {
        int run = 0;
        for (int i = 0; i < nb; i++) { int v = buf[i]; buf[i] = run; run += v; }
    }
    __syncthreads();
    for (int i = t; i < nb; i += 256) bsum[i] = buf[i];
}

__global__ __launch_bounds__(256)
void scan3_kernel(const int* __restrict__ hist, const int* __restrict__ bbase,
                  int* __restrict__ offs, int* __restrict__ cursor, int N) {
    const int t = threadIdx.x, b = blockIdx.x;
    const int base = b * 1024 + t * 4;
    int v[4];
    #pragma unroll
    for (int q = 0; q < 4; q++) v[q] = (base + q < N) ? hist[base + q] : 0;
    const int s = v[0] + v[1] + v[2] + v[3];
    const int lane = t & 63, wid = t >> 6;
    int inc = s;
    #pragma unroll
    for (int off = 1; off < 64; off <<= 1) {
        int u = __shfl_up(inc, off, 64);
        if (lane >= off) inc += u;
    }
    __shared__ int wtot[4];
    if (lane == 63) wtot[wid] = inc;
    __syncthreads();
    int wbase = 0;
    #pragma unroll
    for (int wq = 0; wq < 3; wq++) if (wq < wid) wbase += wtot[wq];
    int run = bbase[b] + wbase + (inc - s);
    #pragma unroll
    for (int q = 0; q < 4; q++) {
        const int i = base + q;
        if (i < N) { cursor[i] = run; run += v[q]; offs[i + 1] = run; }
    }
    if (b == 0 && t == 0) offs[0] = 0;
}

// scatter: rc[slot]=(r,c) single 8B scatter + perm[slot]=e
__global__ void scatter_kernel(const int* __restrict__ rows, const int* __restrict__ cols,
                               int* __restrict__ cursor,
                               int* __restrict__ perm, int2* __restrict__ rc, int E) {
    int e = blockIdx.x * blockDim.x + threadIdx.x;
    if (e < E) {
        int r = rows[e];
        int p = atomicAdd(&cursor[r], 1);
        perm[p] = e;
        rc[p] = make_int2(r, cols[e]);
    }
}

// ------------------------------------------- fallback kernels (atomic path) ---
template<int BLK>
__global__ __launch_bounds__(BLK)
void edge_atomic_kernel(const float* __restrict__ h, const float* __restrict__ x,
                 const float* __restrict__ eattr,
                 const int* __restrict__ rows, const int* __restrict__ cols,
                 const float* __restrict__ we_w1, const float* __restrict__ we_b1,
                 const float* __restrict__ we_w2, const float* __restrict__ we_b2,
                 const float* __restrict__ wx_w1, const float* __restrict__ wx_b1,
                 const float* __restrict__ wx_w2, const float* __restrict__ wx_b2,
                 float* __restrict__ agg, float* __restrict__ cnt, float* __restrict__ mi,
                 int E)
{
    __shared__ float act[64][BLK];
    const int tid = threadIdx.x;
    const int e = blockIdx.x * BLK + tid;
    if (e >= E) return;

    const int r = rows[e];
    const int c = cols[e];
    const float d0 = x[(size_t)r*3+0] - x[(size_t)c*3+0];
    const float d1 = x[(size_t)r*3+1] - x[(size_t)c*3+1];
    const float d2 = x[(size_t)r*3+2] - x[(size_t)c*3+2];
    const float rad = d0*d0 + d1*d1 + d2*d2;

    float A[64];
    #pragma unroll
    for (int j = 0; j < 64; j++) A[j] = we_b1[j];
    const float* hr = h + (size_t)r * 64;
    const float* hc = h + (size_t)c * 64;
    #pragma unroll 4
    for (int k = 0; k < 64; k++) {
        const float a0 = hr[k];
        const float a1 = hc[k];
        const float* w0 = we_w1 + k * 64;
        const float* w1 = we_w1 + (64 + k) * 64;
        #pragma unroll
        for (int j = 0; j < 64; j++) A[j] += a0 * w0[j] + a1 * w1[j];
    }
    {
        const float* w = we_w1 + 128 * 64;
        #pragma unroll
        for (int j = 0; j < 64; j++) A[j] += rad * w[j];
    }
    const float* ea = eattr + (size_t)e * 8;
    #pragma unroll
    for (int k = 0; k < 8; k++) {
        const float a = ea[k];
        const float* w = we_w1 + (129 + k) * 64;
        #pragma unroll
        for (int j = 0; j < 64; j++) A[j] += a * w[j];
    }
    #pragma unroll
    for (int j = 0; j < 64; j++) act[j][tid] = fast_tanh(A[j]);

    float B[64];
    #pragma unroll
    for (int j = 0; j < 64; j++) B[j] = we_b2[j];
    #pragma unroll 4
    for (int k = 0; k < 64; k++) {
        const float a = act[k][tid];
        const float* w = we_w2 + k * 64;
        #pragma unroll
        for (int j = 0; j < 64; j++) B[j] += a * w[j];
    }
    #pragma unroll
    for (int j = 0; j < 64; j++) act[j][tid] = fast_tanh(B[j]);

    #pragma unroll
    for (int j = 0; j < 64; j++) A[j] = wx_b1[j];
    #pragma unroll 4
    for (int k = 0; k < 64; k++) {
        const float a = act[k][tid];
        const float* w = wx_w1 + k * 64;
        #pragma unroll
        for (int j = 0; j < 64; j++) A[j] += a * w[j];
    }
    float px = wx_b2[0];
    #pragma unroll
    for (int j = 0; j < 64; j++) px += fast_tanh(A[j]) * wx_w2[j];
    px = fast_tanh(px);

    atomicAdd(&agg[(size_t)r*3+0], d0 * px);
    atomicAdd(&agg[(size_t)r*3+1], d1 * px);
    atomicAdd(&agg[(size_t)r*3+2], d2 * px);
    atomicAdd(&cnt[r], 1.0f);
    float* mir = mi + (size_t)r * 64;
    #pragma unroll
    for (int j = 0; j < 64; j++) atomicAdd(&mir[j], act[j][tid]);
}

template<int BLK>
__global__ __launch_bounds__(BLK, 2)
void node_fb_kernel(const float* __restrict__ h, const float* __restrict__ x,
                 const float* __restrict__ vel,
                 const float* __restrict__ wh_w1, const float* __restrict__ wh_b1,
                 const float* __restrict__ wh_w2, const float* __restrict__ wh_b2,
                 const float* __restrict__ wv_w1, const float* __restrict__ wv_b1,
                 const float* __restrict__ wv_w2, const float* __restrict__ wv_b2,
                 const float* __restrict__ agg, const float* __restrict__ cnt,
                 const float* __restrict__ mi,
                 float* __restrict__ out_h, float* __restrict__ out_x, float* __restrict__ out_v,
                 int N)
{
    const int n = blockIdx.x * BLK + threadIdx.x;
    if (n >= N) return;

    const float* hn = h + (size_t)n * 64;
    const float* mn = mi + (size_t)n * 64;

    float A[64];
    #pragma unroll
    for (int j = 0; j < 64; j++) A[j] = wv_b1[j];
    #pragma unroll
    for (int k = 0; k < 64; k++) {
        const float a = hn[k];
        const float* w = wv_w1 + k * 64;
        #pragma unroll
        for (int j = 0; j < 64; j++) A[j] += a * w[j];
    }
    float pv = wv_b2[0];
    #pragma unroll
    for (int j = 0; j < 64; j++) pv += fast_tanh(A[j]) * wv_w2[j];

    #pragma unroll
    for (int j = 0; j < 64; j++) A[j] = wh_b1[j];
    #pragma unroll
    for (int k = 0; k < 64; k++) {
        const float a0 = hn[k];
        const float a1 = mn[k];
        const float* w0 = wh_w1 + k * 64;
        const float* w1 = wh_w1 + (64 + k) * 64;
        #pragma unroll
        for (int j = 0; j < 64; j++) A[j] += a0 * w0[j] + a1 * w1[j];
    }
    #pragma unroll
    for (int j = 0; j < 64; j++) A[j] = fast_tanh(A[j]);

    float B[64];
    #pragma unroll
    for (int j = 0; j < 64; j++) B[j] = wh_b2[j];
    #pragma unroll
    for (int k = 0; k < 64; k++) {
        const float a = A[k];
        const float* w = wh_w2 + k * 64;
        #pragma unroll
        for (int j = 0; j < 64; j++) B[j] += a * w[j];
    }
    float* oh = out_h + (size_t)n * 64;
    #pragma unroll
    for (int j = 0; j < 64; j++) oh[j] = B[j];

    const float inv = 1.0f / fmaxf(cnt[n], 1.0f);
    #pragma unroll
    for (int d = 0; d < 3; d++) {
        const float am = agg[(size_t)n*3 + d] * inv;
        const float vn = vel[(size_t)n*3 + d] * pv + am;
        out_v[(size_t)n*3 + d] = vn;
        out_x[(size_t)n*3 + d] = x[(size_t)n*3 + d] + vn;
    }
}

// ------------------------------------------------------------------ launch ---
extern "C" void kernel_launch(void* const* d_in, const int* in_sizes, int n_in,
                              void* d_out, int out_size, void* d_ws, size_t ws_size,
                              hipStream_t stream) {
    const float* h      = (const float*)d_in[0];
    const float* x      = (const float*)d_in[1];
    const float* vel    = (const float*)d_in[2];
    const float* eattr  = (const float*)d_in[3];
    const float* we_w1  = (const float*)d_in[4];
    const float* we_b1  = (const float*)d_in[5];
    const float* we_w2  = (const float*)d_in[6];
    const float* we_b2  = (const float*)d_in[7];
    const float* wx_w1  = (const float*)d_in[8];
    const float* wx_b1  = (const float*)d_in[9];
    const float* wx_w2  = (const float*)d_in[10];
    const float* wx_b2  = (const float*)d_in[11];
    const float* wh_w1  = (const float*)d_in[12];
    const float* wh_b1  = (const float*)d_in[13];
    const float* wh_w2  = (const float*)d_in[14];
    const float* wh_b2  = (const float*)d_in[15];
    const float* wv_w1  = (const float*)d_in[16];
    const float* wv_b1  = (const float*)d_in[17];
    const float* wv_w2  = (const float*)d_in[18];
    const float* wv_b2  = (const float*)d_in[19];
    const int*   ar     = (const int*)d_in[20];

    const int N = in_sizes[0] / 64;
    const int E = in_sizes[20] / 2;
    const int* rows = ar;
    const int* cols = ar + E;

    float* out_h = (float*)d_out;            // N*64 (HrB/HcB bf16 scratch first)
    float* out_x = out_h + (size_t)N * 64;   // N*3
    float* out_v = out_x + (size_t)N * 3;    // N*3

    u16* HrB = (u16*)d_out;
    u16* HcB = HrB + (size_t)N * 64;

    const int nbScan = (N + 1023) / 1024;

    // --- workspace layout: ~48 MB. miF..hist contiguous -> ONE memset ---
    char* p = (char*)d_ws;
    float* miF  = (float*)p; p += (size_t)N * 64 * sizeof(float);
    float* aggF = (float*)p; p += (size_t)N * 3 * sizeof(float);
    float* cntF = (float*)p; p += (size_t)N * sizeof(float);
    int*  hist  = (int*)p;   p += (size_t)N * sizeof(int);
    const size_t zero_bytes = (size_t)(p - (char*)d_ws);
    int*  offs  = (int*)p;   p += (size_t)(N + 1) * sizeof(int);
    int*  cursor= (int*)p;   p += (size_t)N * sizeof(int);
    int*  bsum  = (int*)p;   p += (size_t)(nbScan > 0 ? nbScan : 1) * sizeof(int);
    int*  perm  = (int*)p;   p += (size_t)E * sizeof(int);
    p = (char*)(((uintptr_t)p + 7) & ~(uintptr_t)7);
    int2* rc    = (int2*)p;  p += (size_t)E * sizeof(int2);
    p = (char*)(((uintptr_t)p + 63) & ~(uintptr_t)63);
    u16*  we1t = (u16*)p;   p += 64 * 128 * sizeof(u16);
    u16*  we2t = (u16*)p;   p += 64 * 64 * sizeof(u16);
    u16*  wx1t = (u16*)p;   p += 64 * 64 * sizeof(u16);
    u16*  wv1t = (u16*)p;   p += 64 * 64 * sizeof(u16);
    u16*  wh1t = (u16*)p;   p += 64 * 128 * sizeof(u16);
    u16*  wh2t = (u16*)p;   p += 64 * 64 * sizeof(u16);
    u16*  wert = (u16*)p;   p += 64 * 32 * sizeof(u16);
    const size_t needed = (size_t)(p - (char*)d_ws);

    if (ws_size >= needed && nbScan <= 1024) {
        hipMemsetAsync(d_ws, 0, zero_bytes, stream);
        hist_kernel<<<(E + 255) / 256, 256, 0, stream>>>(rows, hist, E);
        scan1_kernel<<<nbScan, 256, 0, stream>>>(hist, bsum, N);
        scan2_kernel<<<1, 256, 0, stream>>>(bsum, nbScan);
        scan3_kernel<<<nbScan, 256, 0, stream>>>(hist, bsum, offs, cursor, N);
        scatter_kernel<<<(E + 255) / 256, 256, 0, stream>>>(rows, cols, cursor, perm, rc, E);

        wprep_kernel<<<32, 256, 0, stream>>>(we_w1, we_w2, wx_w1, wv_w1, wh_w1, wh_w2,
                                             we1t, we2t, wx1t, wv1t, wh1t, wh2t, wert);
        pre_mfma_kernel<<<(N + 63) / 64, 256, 0, stream>>>(h, we_b1, we1t, HrB, HcB, N);

        edge_mfma_kernel<<<(E + 63) / 64, 256, 0, stream>>>(
            x, eattr, perm, rc, HrB, HcB,
            wert, we2t, we_b2, wx1t, wx_b1, wx_w2, wx_b2,
            miF, aggF, cntF, E);

        aggnode_kernel<<<(N + 63) / 64, 256, 0, stream>>>(
            h, x, vel, miF, aggF, cntF,
            wv1t, wv_b1, wv_w2, wv_b2,
            wh1t, wh_b1, wh2t, wh_b2,
            out_h, out_x, out_v, N);
    } else {
        // --- fallback: atomic path ---
        float* agg2 = (float*)d_ws;               // N*3
        float* cnt2 = agg2 + (size_t)N * 3;       // N
        float* mi2  = cnt2 + N;                   // N*64
        hipMemsetAsync(d_ws, 0, (size_t)N * 68 * sizeof(float), stream);

        edge_atomic_kernel<128><<<(E + 127) / 128, 128, 0, stream>>>(
            h, x, eattr, rows, cols,
            we_w1, we_b1, we_w2, we_b2,
            wx_w1, wx_b1, wx_w2, wx_b2,
            agg2, cnt2, mi2, E);

        node_fb_kernel<128><<<(N + 127) / 128, 128, 0, stream>>>(
            h, x, vel,
            wh_w1, wh_b1, wh_w2, wh_b2,
            wv_w1, wv_b1, wv_w2, wv_b2,
            agg2, cnt2, mi2, out_h, out_x, out_v, N);
    }
}